// Round 2
// baseline (3209.494 us; speedup 1.0000x reference)
//
#include <hip/hip_runtime.h>
#include <math.h>

namespace {

constexpr int Bn = 8, Sn = 1024, Dn = 768, Hn = 12, DHn = 64, Fn = 3072;
constexpr int Mrows = Bn * Sn;  // 8192 token rows

// ---------------------------------------------------------------------------
// SGEMM: C[M,N] = epi(A[M,K] @ W[K,N] + bias[N] [+ res[M,N]])
// 128x128 tile, BK=8, 256 threads, 8x8 micro-tile per thread.
// EPI: 0 = none, 1 = exact erf-GELU, 2 = add residual
// ---------------------------------------------------------------------------
template <int EPI>
__global__ __launch_bounds__(256) void sgemm_kernel(
    const float* __restrict__ A, const float* __restrict__ W,
    const float* __restrict__ bias, const float* __restrict__ res,
    float* __restrict__ C, int M, int N, int K) {
  __shared__ float As[8][128];  // transposed A tile: As[k][m]
  __shared__ float Bs[8][128];

  const int tid = threadIdx.x;
  const int bn = blockIdx.x, bm = blockIdx.y;
  const int tx = tid & 15, ty = tid >> 4;

  // global->LDS load mapping (one float4 per thread per tile)
  const int a_row = tid >> 1, a_k = (tid & 1) << 2;   // A: 128 rows x 8 k
  const int b_k = tid >> 5, b_c = (tid & 31) << 2;    // B: 8 k x 128 cols
  const float* Ap = A + (size_t)(bm * 128 + a_row) * K + a_k;
  const float* Wp = W + (size_t)b_k * N + bn * 128 + b_c;

  float acc[8][8];
#pragma unroll
  for (int i = 0; i < 8; ++i)
#pragma unroll
    for (int j = 0; j < 8; ++j) acc[i][j] = 0.f;

  for (int k0 = 0; k0 < K; k0 += 8) {
    const float4 av = *(const float4*)(Ap + k0);
    const float4 wv = *(const float4*)(Wp + (size_t)k0 * N);
    __syncthreads();  // protect previous tile readers
    As[a_k + 0][a_row] = av.x;
    As[a_k + 1][a_row] = av.y;
    As[a_k + 2][a_row] = av.z;
    As[a_k + 3][a_row] = av.w;
    *(float4*)&Bs[b_k][b_c] = wv;
    __syncthreads();
#pragma unroll
    for (int kk = 0; kk < 8; ++kk) {
      const float4 aLo = *(const float4*)&As[kk][ty * 8];
      const float4 aHi = *(const float4*)&As[kk][ty * 8 + 4];
      const float4 bLo = *(const float4*)&Bs[kk][tx * 8];
      const float4 bHi = *(const float4*)&Bs[kk][tx * 8 + 4];
      const float a0[8] = {aLo.x, aLo.y, aLo.z, aLo.w, aHi.x, aHi.y, aHi.z, aHi.w};
      const float b0[8] = {bLo.x, bLo.y, bLo.z, bLo.w, bHi.x, bHi.y, bHi.z, bHi.w};
#pragma unroll
      for (int i = 0; i < 8; ++i)
#pragma unroll
        for (int j = 0; j < 8; ++j) acc[i][j] += a0[i] * b0[j];
    }
  }

  float bcol[8];
#pragma unroll
  for (int j = 0; j < 8; ++j) bcol[j] = bias[bn * 128 + tx * 8 + j];

#pragma unroll
  for (int i = 0; i < 8; ++i) {
    const int row = bm * 128 + ty * 8 + i;
    const size_t base = (size_t)row * N + bn * 128 + tx * 8;
#pragma unroll
    for (int jv = 0; jv < 2; ++jv) {
      float t0 = acc[i][jv * 4 + 0] + bcol[jv * 4 + 0];
      float t1 = acc[i][jv * 4 + 1] + bcol[jv * 4 + 1];
      float t2 = acc[i][jv * 4 + 2] + bcol[jv * 4 + 2];
      float t3 = acc[i][jv * 4 + 3] + bcol[jv * 4 + 3];
      if (EPI == 1) {
        t0 = 0.5f * t0 * (1.f + erff(t0 * 0.70710678118654752f));
        t1 = 0.5f * t1 * (1.f + erff(t1 * 0.70710678118654752f));
        t2 = 0.5f * t2 * (1.f + erff(t2 * 0.70710678118654752f));
        t3 = 0.5f * t3 * (1.f + erff(t3 * 0.70710678118654752f));
      }
      if (EPI == 2) {
        const float4 rv = *(const float4*)(res + base + jv * 4);
        t0 += rv.x; t1 += rv.y; t2 += rv.z; t3 += rv.w;
      }
      float4 o;
      o.x = t0; o.y = t1; o.z = t2; o.w = t3;
      *(float4*)(C + base + jv * 4) = o;
    }
  }
}

// ---------------------------------------------------------------------------
// Fused attention: per block = (b, h, 8 query rows).
//   scores = q.k^T/8 + mask*(-1e9) + adjoin  -> softmax -> write attn -> PV
// Wave w owns j-quarter [256w,256w+256) for scores/PV; rows 2w,2w+1 for softmax.
// ---------------------------------------------------------------------------
__global__ __launch_bounds__(256) void attn_kernel(
    const float* __restrict__ q, const float* __restrict__ k,
    const float* __restrict__ v, const float* __restrict__ mask,
    const float* __restrict__ adjoin, float* __restrict__ attn,
    float* __restrict__ ctx) {
  __shared__ float s_sc[8][1024];      // 32 KB score tile
  __shared__ float s_q[8][64];         // 2 KB q tile
  __shared__ float s_red[4][8][64];    // 8 KB cross-wave PV reduction
  __shared__ float s_inv[8];

  const int tid = threadIdx.x;
  const int bid = blockIdx.x;
  const int it = bid & 127;            // S/8 = 128 i-tiles; consecutive bids share (b,h)
  const int h = (bid >> 7) % Hn;
  const int b = bid / (128 * Hn);
  const int i0 = it * 8;
  const int w = tid >> 6, l = tid & 63;

  if (tid < 128) {
    const int row = tid >> 4, d4 = tid & 15;
    *(float4*)&s_q[row][d4 * 4] =
        *(const float4*)(q + (size_t)(b * Sn + i0 + row) * Dn + h * DHn + d4 * 4);
  }
  __syncthreads();

  const float* kbase = k + (size_t)b * Sn * Dn + h * DHn;
  const float* vbase = v + (size_t)b * Sn * Dn + h * DHn;

  // ---- scores ----
  for (int c = 0; c < 4; ++c) {
    const int j = (w << 8) + (c << 6) + l;
    const float4* k4 = (const float4*)(kbase + (size_t)j * Dn);
    float dot[8];
#pragma unroll
    for (int r = 0; r < 8; ++r) dot[r] = 0.f;
#pragma unroll
    for (int f = 0; f < 16; ++f) {
      const float4 kv = k4[f];
#pragma unroll
      for (int r = 0; r < 8; ++r) {
        const float4 qv = *(const float4*)&s_q[r][f * 4];
        dot[r] += qv.x * kv.x + qv.y * kv.y + qv.z * kv.z + qv.w * kv.w;
      }
    }
    const float mval = mask[b * Sn + j] * (-1e9f);
#pragma unroll
    for (int r = 0; r < 8; ++r) {
      const float adj = adjoin[((size_t)b * Sn + i0 + r) * Sn + j];
      s_sc[r][j] = dot[r] * 0.125f + mval + adj;
    }
  }
  __syncthreads();

  // ---- softmax (wave w owns rows 2w, 2w+1) + normalized attn write ----
  const size_t attnrow_base = ((size_t)(b * Hn + h) * Sn + i0) * Sn;
#pragma unroll
  for (int rr = 0; rr < 2; ++rr) {
    const int r = 2 * w + rr;
    float m = -INFINITY;
    for (int c = 0; c < 16; ++c) m = fmaxf(m, s_sc[r][(c << 6) + l]);
#pragma unroll
    for (int off = 32; off > 0; off >>= 1) m = fmaxf(m, __shfl_xor(m, off));
    float ssum = 0.f;
    for (int c = 0; c < 16; ++c) {
      const float e = expf(s_sc[r][(c << 6) + l] - m);
      s_sc[r][(c << 6) + l] = e;  // keep unnormalized in LDS
      ssum += e;
    }
#pragma unroll
    for (int off = 32; off > 0; off >>= 1) ssum += __shfl_xor(ssum, off);
    const float inv = 1.0f / ssum;
    if (l == 0) s_inv[r] = inv;
    for (int c = 0; c < 16; ++c) {
      const int j = (c << 6) + l;
      attn[attnrow_base + (size_t)r * Sn + j] = s_sc[r][j] * inv;
    }
  }
  __syncthreads();

  // ---- PV: wave w covers its j-quarter for all 8 rows ----
  const int d4 = l & 15, jsub = l >> 4;
  float pv[8][4];
#pragma unroll
  for (int r = 0; r < 8; ++r)
#pragma unroll
    for (int d = 0; d < 4; ++d) pv[r][d] = 0.f;

  for (int jj = 0; jj < 64; ++jj) {
    const int j = (w << 8) + jsub + (jj << 2);
    const float4 vv = *(const float4*)(vbase + (size_t)j * Dn + d4 * 4);
#pragma unroll
    for (int r = 0; r < 8; ++r) {
      const float p = s_sc[r][j];
      pv[r][0] += p * vv.x;
      pv[r][1] += p * vv.y;
      pv[r][2] += p * vv.z;
      pv[r][3] += p * vv.w;
    }
  }
#pragma unroll
  for (int r = 0; r < 8; ++r)
#pragma unroll
    for (int d = 0; d < 4; ++d) {
      float x2 = pv[r][d];
      x2 += __shfl_xor(x2, 16);
      x2 += __shfl_xor(x2, 32);
      pv[r][d] = x2;
    }
  if (jsub == 0) {
#pragma unroll
    for (int r = 0; r < 8; ++r) {
      float4 t4;
      t4.x = pv[r][0]; t4.y = pv[r][1]; t4.z = pv[r][2]; t4.w = pv[r][3];
      *(float4*)&s_red[w][r][d4 * 4] = t4;
    }
  }
  __syncthreads();

#pragma unroll
  for (int o = 0; o < 2; ++o) {
    const int idx = tid + (o << 8);
    const int r = idx >> 6, d = idx & 63;
    const float val =
        (s_red[0][r][d] + s_red[1][r][d] + s_red[2][r][d] + s_red[3][r][d]) *
        s_inv[r];
    ctx[(size_t)(b * Sn + i0 + r) * Dn + h * DHn + d] = val;
  }
}

// ---------------------------------------------------------------------------
// LayerNorm over last dim (768), one block per row.
// ---------------------------------------------------------------------------
__global__ __launch_bounds__(256) void ln_kernel(
    const float* __restrict__ xin, const float* __restrict__ gamma,
    const float* __restrict__ beta, float* __restrict__ out) {
  const int row = blockIdx.x;
  const float* xr = xin + (size_t)row * Dn;
  const int tid = threadIdx.x;
  const float v0 = xr[tid];
  const float v1 = xr[tid + 256];
  const float v2 = xr[tid + 512];
  float s = v0 + v1 + v2;
  float s2 = v0 * v0 + v1 * v1 + v2 * v2;
#pragma unroll
  for (int off = 32; off > 0; off >>= 1) {
    s += __shfl_xor(s, off);
    s2 += __shfl_xor(s2, off);
  }
  __shared__ float red[2][4];
  const int w = tid >> 6, l = tid & 63;
  if (l == 0) {
    red[0][w] = s;
    red[1][w] = s2;
  }
  __syncthreads();
  s = red[0][0] + red[0][1] + red[0][2] + red[0][3];
  s2 = red[1][0] + red[1][1] + red[1][2] + red[1][3];
  const float mu = s * (1.f / 768.f);
  const float var = s2 * (1.f / 768.f) - mu * mu;
  const float inv = 1.0f / sqrtf(var + 1e-6f);
  out[(size_t)row * Dn + tid] = (v0 - mu) * inv * gamma[tid] + beta[tid];
  out[(size_t)row * Dn + tid + 256] =
      (v1 - mu) * inv * gamma[tid + 256] + beta[tid + 256];
  out[(size_t)row * Dn + tid + 512] =
      (v2 - mu) * inv * gamma[tid + 512] + beta[tid + 512];
}

}  // namespace

extern "C" void kernel_launch(void* const* d_in, const int* in_sizes, int n_in,
                              void* d_out, int out_size, void* d_ws,
                              size_t ws_size, hipStream_t stream) {
  const float* x = (const float*)d_in[0];
  // d_in[1] = training (int, 0) — dropout inactive, ignored.
  const float* mask = (const float*)d_in[2];
  const float* adjoin = (const float*)d_in[3];
  const float* Wq = (const float*)d_in[4];
  const float* bq = (const float*)d_in[5];
  const float* Wk = (const float*)d_in[6];
  const float* bk = (const float*)d_in[7];
  const float* Wv = (const float*)d_in[8];
  const float* bv = (const float*)d_in[9];
  const float* Wo = (const float*)d_in[10];
  const float* bo = (const float*)d_in[11];
  const float* W1 = (const float*)d_in[12];
  const float* b1 = (const float*)d_in[13];
  const float* W2 = (const float*)d_in[14];
  const float* b2 = (const float*)d_in[15];
  const float* gamma2 = (const float*)d_in[16];
  const float* beta2 = (const float*)d_in[17];

  float* out2 = (float*)d_out;                      // [B,S,D]
  float* attn = out2 + (size_t)Mrows * Dn;          // [B,H,S,S]

  // workspace layout (floats); peak use = 31457280 floats = 125.8 MB
  float* ws = (float*)d_ws;
  const size_t SZ_D = (size_t)Mrows * Dn;           // 6291456
  float* qb = ws;                                   // [0, SZ_D)
  float* kb = ws + SZ_D;                            // [SZ_D, 2SZ_D)
  float* vb = ws + 2 * SZ_D;                        // [2SZ_D, 3SZ_D)
  float* ctx = ws + 3 * SZ_D;                       // [3SZ_D, 4SZ_D)
  float* out1 = ws;                                 // reuse q (dead after attn)
  float* hb = ws + SZ_D;                            // reuse k,v,ctx (dead after Wo GEMM)

  const dim3 blk(256);
  const dim3 gD(Dn / 128, Mrows / 128);   // (6,64)
  const dim3 gF(Fn / 128, Mrows / 128);   // (24,64)

  // QKV projections
  sgemm_kernel<0><<<gD, blk, 0, stream>>>(x, Wq, bq, nullptr, qb, Mrows, Dn, Dn);
  sgemm_kernel<0><<<gD, blk, 0, stream>>>(x, Wk, bk, nullptr, kb, Mrows, Dn, Dn);
  sgemm_kernel<0><<<gD, blk, 0, stream>>>(x, Wv, bv, nullptr, vb, Mrows, Dn, Dn);

  // fused attention (writes attn output + ctx)
  attn_kernel<<<dim3(Bn * Hn * (Sn / 8)), blk, 0, stream>>>(qb, kb, vb, mask,
                                                            adjoin, attn, ctx);

  // out1 = x + ctx @ Wo + bo
  sgemm_kernel<2><<<gD, blk, 0, stream>>>(ctx, Wo, bo, x, out1, Mrows, Dn, Dn);
  // h = gelu(out1 @ W1 + b1)
  sgemm_kernel<1><<<gF, blk, 0, stream>>>(out1, W1, b1, nullptr, hb, Mrows, Fn, Dn);
  // out1 += h @ W2 + b2   (in-place residual sum)
  sgemm_kernel<2><<<gD, blk, 0, stream>>>(hb, W2, b2, out1, out1, Mrows, Dn, Fn);

  // out2 = layernorm(out1)
  ln_kernel<<<dim3(Mrows), blk, 0, stream>>>(out1, gamma2, beta2, out2);
}